// Round 8
// baseline (115.688 us; speedup 1.0000x reference)
//
#include <hip/hip_runtime.h>

#define NQ  12
#define DIM 4096
#define TPB 256

typedef float v2f __attribute__((ext_vector_type(2)));
typedef float v4f __attribute__((ext_vector_type(4)));

// ---------------------------------------------------------------------------
// 2-state persistent blocks (grid 2048): both tiles' global loads issue at
// kernel entry -> tile-1 HBM latency hides under tile-0 compute, tile-0 NT
// store drain hides under tile-1 compute, launch overhead halves, and the
// global load/compute/store phase-lockstep of a 4096-block launch is broken.
// Passes/swizzle identical to round-7 (measured-correct): 256 thr x 16 amps,
// 4 passes, slot(e) = e ^ (((e>>5)&7)<<1), 32768 B LDS -> 5 blocks/CU.
// Norm partials are REPLICATED into each wave's 8 KiB slab (wave w writes its
// partial to all 4 slabs before bar1; each wave reads only its OWN slab,
// whose bytes only itself overwrites afterwards) -> old bar2 eliminated:
// cross-wave safety from bar1, intra-wave read-before-write from DS program
// order. Barriers: 5 per 2 states (bar1-t0, pre-P4-t0, barA, bar1-t1,
// pre-P4-t1).  P1->P2, P2->P3 stay barrier-free (wave-slab-local, round 7).
// ---------------------------------------------------------------------------

__device__ __forceinline__ float wave_reduce(float v) {
#pragma unroll
    for (int m = 32; m >= 1; m >>= 1) v += __shfl_xor(v, m, 64);
    return v;
}

// broadcast lane q's value to all lanes (lands in SGPR)
#define BCAST(v, q) __uint_as_float(__builtin_amdgcn_readlane(__float_as_uint(v), (q)))

// One circuit layer: unnormalized H on register-bit MC (1/sqrt2 folded into
// epilogue), then (X*RX if XGATE else RX) on bit MT where MC==1.
// ctv = (c,c), snv = (s,-s); off-diag = -i*s, so (-i*s)*z = snv * z.yx.
template <int MC, int MT, bool XGATE>
__device__ __forceinline__ void apply_layer(v2f* a, v2f ctv, v2f snv) {
#pragma unroll
    for (int i = 0; i < 16; ++i) {
        if (i & MC) continue;
        const int j = i | MC;
        const v2f t0 = a[i], t1 = a[j];
        a[i] = t0 + t1;          // v_pk_add_f32
        a[j] = t0 - t1;
    }
#pragma unroll
    for (int i = 0; i < 16; ++i) {
        if (!(i & MC) || (i & MT)) continue;   // control=1, target=0 slot
        const int j = i | MT;
        const v2f b0 = a[i], b1 = a[j];
        const v2f s0 = snv * b0.yx;            // v_pk_mul_f32
        const v2f s1 = snv * b1.yx;
        if (XGATE) {                           // X*RX = [[s, c],[c, s]]
            a[i] = ctv * b1 + s0;              // v_pk_fma_f32
            a[j] = ctv * b0 + s1;
        } else {                               // RX = [[c, s],[s, c]]
            a[i] = ctv * b0 + s1;
            a[j] = ctv * b1 + s0;
        }
    }
}

#define CTV(q) ({ v2f _c; _c.x = BCAST(cl, q); _c.y = _c.x; _c; })
#define SNV(q) ({ float _s = BCAST(sl, q); v2f _v; _v.x = _s; _v.y = -_s; _v; })

// Encode + 4 passes + probs epilogue for one 4096-amp state.
// Contains ONE barrier (pre-P4). Caller provides bar1-separated partials
// already consumed into invd.
__device__ __forceinline__ void run_tile(const float4* xv, float invd,
                                         char* lds, int t,
                                         float cl, float sl,
                                         float* __restrict__ outb) {
    // ---- encoding: re = clamp(v,-1,1); im = sign(v)*sqrt(1-re^2) ----
    // |q|^2 == 1 exactly => second normalization = 1/4096, folded into epilogue.
    v2f a[16];
#define ENC(k, xval)                                                      \
    {                                                                     \
        const float v   = (xval) * invd;                                  \
        const float re  = fminf(fmaxf(v, -1.0f), 1.0f);                   \
        const float imb = __builtin_amdgcn_sqrtf(fmaxf(1.0f - re * re, 0.f)); \
        const float im  = (v > 0.f) ? imb : ((v < 0.f) ? -imb : 0.f);     \
        v2f q; q.x = re; q.y = im;                                        \
        a[k] = q;                                                         \
    }
#pragma unroll
    for (int j = 0; j < 4; ++j) {
        const float4 xq = xv[j];
        ENC(4 * j + 0, xq.x); ENC(4 * j + 1, xq.y);
        ENC(4 * j + 2, xq.z); ENC(4 * j + 3, xq.w);
    }
#undef ENC

    // ---- pass 1: layers 0..2 on idx bits {0,1,2,3}; e = 16t + 2k + b0 ----
    apply_layer<1, 2, true>(a, CTV(0), SNV(0));
    apply_layer<2, 4, true>(a, CTV(1), SNV(1));
    apply_layer<4, 8, true>(a, CTV(2), SNV(2));
    {
        // e>>5 = t>>1; xor bits fold as byte = 128t | ((k ^ ((t>>1)&7))<<4)
        const int v1b = (t << 7) | (((t >> 1) & 7) << 4);
#pragma unroll
        for (int k = 0; k < 8; ++k) {
            v4f w; w.x = a[2 * k].x; w.y = a[2 * k].y;
            w.z = a[2 * k + 1].x; w.w = a[2 * k + 1].y;
            *(v4f*)(lds + (v1b ^ (k << 4))) = w;
        }
    }
    // NO barrier: P1 write / P2 read are wave-slab-local ([8192w, 8192w+8192))

    // ---- pass 2: layers 3..5 on idx bits {3,4,5,6}; e = (t&7) + 8r + 128g ----
    {
        // e>>5 = (r>>2) + 4g ; slot bit3 = (r&1)^(g&1), bits1-2 ^= (r>>2)
        const int g  = t >> 3;
        const int gp2 = g & 1;
        const int baseE = ((t & 7) << 3) + (g << 10) + (gp2 << 6);        // r even
        const int baseO = ((t & 7) << 3) + (g << 10) + ((1 - gp2) << 6);  // r odd
#pragma unroll
        for (int r = 0; r < 16; ++r)
            a[r] = *(const v2f*)(lds +
                ((((r & 1) ? baseO : baseE) ^ ((r >> 2) << 4)) + ((r >> 1) << 7)));
        apply_layer<1, 2, true>(a, CTV(3), SNV(3));
        apply_layer<2, 4, true>(a, CTV(4), SNV(4));
        apply_layer<4, 8, true>(a, CTV(5), SNV(5));
#pragma unroll
        for (int r = 0; r < 16; ++r)
            *(v2f*)(lds +
                ((((r & 1) ? baseO : baseE) ^ ((r >> 2) << 4)) + ((r >> 1) << 7))) = a[r];
    }
    // NO barrier: P2 write / P3 read are wave-slab-local

    // ---- pass 3: layers 6..8 on idx bits {6,7,8,9}; e = (t&63) + 64r + 1024w ----
    {
        // e>>5 = ((t>>5)&1) + 2r + 32w ; slot bit1 ^= (t>>5)&1, bits2-3 ^= r&3
        const int b3b = (((t & 63) ^ (((t >> 5) & 1) << 1)) << 3) + ((t >> 6) << 13);
#pragma unroll
        for (int r = 0; r < 16; ++r)
            a[r] = *(const v2f*)(lds + ((b3b ^ ((r & 3) << 5)) + (r << 9)));
        apply_layer<1, 2, true>(a, CTV(6), SNV(6));
        apply_layer<2, 4, true>(a, CTV(7), SNV(7));
        apply_layer<4, 8, true>(a, CTV(8), SNV(8));
#pragma unroll
        for (int r = 0; r < 16; ++r)
            *(v2f*)(lds + ((b3b ^ ((r & 3) << 5)) + (r << 9))) = a[r];
    }
    __syncthreads();   // pre-P4: REQUIRED -- P4 reads span all waves' slabs

    // ---- pass 4: layers 9..11 on idx bits {9,10,11,0}; e = 2t + 512k + b0 ----
    {
        // e>>5 = (t>>4) + 16k ; xor term depends only on t:
        // byte = (16t ^ (((t>>4)&7)<<4)) + 4096k ; (b0=0,b0=1) adjacent -> b128
        const int F0b = (t << 4) ^ (((t >> 4) & 7) << 4);
#pragma unroll
        for (int k = 0; k < 8; ++k) {
            const v4f v = *(const v4f*)(lds + (F0b + (k << 12)));
            v2f q0; q0.x = v.x; q0.y = v.y;
            v2f q1; q1.x = v.z; q1.y = v.w;
            a[k] = q0;       // bit0 = 0
            a[k + 8] = q1;   // bit0 = 1
        }
        apply_layer<1, 2, true >(a, CTV(9),  SNV(9));   // c=b9,  t=b10
        apply_layer<2, 4, true >(a, CTV(10), SNV(10));  // c=b10, t=b11
        apply_layer<4, 8, false>(a, CTV(11), SNV(11));  // c=b11, t=b0

        // probs epilogue; scale = 1/4096 (encode norm) * (1/sqrt2)^24 = 2^-24
        // non-temporal: 64 MB write stream, never re-read -> don't churn L2.
        v2f sc2; sc2.x = 0x1p-24f; sc2.y = 0x1p-24f;
        v2f* outp = (v2f*)outb;
#pragma unroll
        for (int k = 0; k < 8; ++k) {
            const v2f q0 = a[k] * a[k];             // v_pk_mul_f32
            const v2f q1 = a[k | 8] * a[k | 8];
            v2f res; res.x = q0.x + q0.y;
            res.y = q1.x + q1.y;
            res = res * sc2;                        // v_pk_mul_f32
            __builtin_nontemporal_store(res, outp + t + (k << 8));
        }
    }
}

__global__ __launch_bounds__(TPB, 5) void qlayer_kernel(
        const float* __restrict__ state, const float* __restrict__ params,
        float* __restrict__ out) {
    __shared__ __align__(16) v2f amp[DIM];     // 32768 B exactly -> 5 blocks/CU
    char* const lds = (char*)amp;

    const int t = threadIdx.x;
    const int lane = t & 63;
    const int wv = t >> 6;
    const long long sbase0 = (long long)blockIdx.x * (2 * DIM);
    const long long sbase1 = sbase0 + DIM;

    // ---- issue BOTH tiles' loads up front (tile-1 latency hides under
    // tile-0 compute); 8 x global_load_dwordx4, +16 VGPR held for xv1 ----
    const float4* gp0 = (const float4*)(state + sbase0 + t * 16);
    const float4* gp1 = (const float4*)(state + sbase1 + t * 16);
    float4 xv0[4], xv1[4];
#pragma unroll
    for (int j = 0; j < 4; ++j) xv0[j] = gp0[j];
#pragma unroll
    for (int j = 0; j < 4; ++j) xv1[j] = gp1[j];

    // per-lane angle (lanes 0..11 hold cos/sin(theta_q/2)); broadcast via readlane
    const float th = params[lane < NQ ? lane : 0] * 0.5f;
    const float cl = cosf(th);
    const float sl = sinf(th);

    float ss0 = 0.f, ss1 = 0.f;
#pragma unroll
    for (int j = 0; j < 4; ++j) {
        const float4 v = xv0[j];
        ss0 = fmaf(v.x, v.x, ss0); ss0 = fmaf(v.y, v.y, ss0);
        ss0 = fmaf(v.z, v.z, ss0); ss0 = fmaf(v.w, v.w, ss0);
    }
#pragma unroll
    for (int j = 0; j < 4; ++j) {
        const float4 v = xv1[j];
        ss1 = fmaf(v.x, v.x, ss1); ss1 = fmaf(v.y, v.y, ss1);
        ss1 = fmaf(v.z, v.z, ss1); ss1 = fmaf(v.w, v.w, ss1);
    }
    ss0 = wave_reduce(ss0);
    ss1 = wave_reduce(ss1);   // register-only; ready for tile 1 later

    // replicate tile-0 partials into every wave's slab (wave w -> slot 4w)
    if (lane == 0) {
#pragma unroll
        for (int s = 0; s < 4; ++s) *(float*)(lds + 8192 * s + 4 * wv) = ss0;
    }
    __syncthreads();                           // bar1-t0: all partials visible
    {
        const float* p = (const float*)(lds + 8192 * wv);   // own slab: broadcast read
        const float invd0 = __builtin_amdgcn_rsqf(p[0] + p[1] + p[2] + p[3]);
        // own-wave DS order guarantees this read precedes own P1 writes; no
        // other wave touches this slab after bar1 -> no second barrier needed.
        run_tile(xv0, invd0, lds, t, cl, sl, out + sbase0);
    }
    __syncthreads();                           // barA: t0 P4 reads complete

    // replicate tile-1 partials (reduction already done in registers)
    if (lane == 0) {
#pragma unroll
        for (int s = 0; s < 4; ++s) *(float*)(lds + 8192 * s + 4 * wv) = ss1;
    }
    __syncthreads();                           // bar1-t1
    {
        const float* p = (const float*)(lds + 8192 * wv);
        const float invd1 = __builtin_amdgcn_rsqf(p[0] + p[1] + p[2] + p[3]);
        run_tile(xv1, invd1, lds, t, cl, sl, out + sbase1);
    }
}

extern "C" void kernel_launch(void* const* d_in, const int* in_sizes, int n_in,
                              void* d_out, int out_size, void* d_ws, size_t ws_size,
                              hipStream_t stream) {
    (void)in_sizes; (void)n_in; (void)out_size; (void)d_ws; (void)ws_size;
    const float* state  = (const float*)d_in[0];   // (8,512,4096) fp32
    const float* params = (const float*)d_in[1];   // (12,) fp32
    float* out = (float*)d_out;                    // (8,512,4096) fp32
    qlayer_kernel<<<dim3(2048), dim3(TPB), 0, stream>>>(state, params, out);
}

// Round 9
// 115.181 us; speedup vs baseline: 1.0044x; 1.0044x over previous
//
#include <hip/hip_runtime.h>

#define NQ  12
#define DIM 4096
#define TPB 256

typedef float v2f __attribute__((ext_vector_type(2)));
typedef float v4f __attribute__((ext_vector_type(4)));

// ---------------------------------------------------------------------------
// Round-7 structure (measured-best family, ~115 us harness): 256 thr x 16
// amps, 4 passes, swizzle slot(e) = e ^ (((e>>5)&7)<<1), 32768 B LDS -> 5
// blocks/CU, barriers {bar1, bar2, pre-P4}.
//
// NEW this round: FORCED packed-fp32 gate math. VALUBusy evidence (18-19 us
// busy vs 8.5 us packed-op model = 2.15x) says hipcc scalarizes float2
// arithmetic (v_pk_*_f32 formation is weak in LLVM AMDGPU). Inline-asm VOP3P:
//   pk_add / pk_sub (neg_lo+neg_hi)   -- H butterfly
//   pk_mul_swap: v_pk_mul_f32 op_sel:[0,1] op_sel_hi:[1,0]  = a * b.yx
//     (fuses the .yx swizzle of the -i*s off-diagonal into the mul)
//   pk_fma                             -- diag*amp + offdiag
// 12 layers x 32 packed ops = 384 (vs ~768+ scalar), epilogue squares packed.
// Scheduling lessons (rounds 3,5,7,8 all neutral/negative): no x-staging, no
// all-b128, no extra pipelining; keep this shape.
// ---------------------------------------------------------------------------

__device__ __forceinline__ float wave_reduce(float v) {
#pragma unroll
    for (int m = 32; m >= 1; m >>= 1) v += __shfl_xor(v, m, 64);
    return v;
}

// broadcast lane q's value to all lanes (lands in SGPR)
#define BCAST(v, q) __uint_as_float(__builtin_amdgcn_readlane(__float_as_uint(v), (q)))

// ---- forced VOP3P packed-fp32 ops (gfx90a+/gfx950) ----
__device__ __forceinline__ v2f pk_add(v2f a, v2f b) {
    v2f d;
    asm("v_pk_add_f32 %0, %1, %2" : "=v"(d) : "v"(a), "v"(b));
    return d;
}
__device__ __forceinline__ v2f pk_sub(v2f a, v2f b) {   // a - b
    v2f d;
    asm("v_pk_add_f32 %0, %1, %2 neg_lo:[0,1] neg_hi:[0,1]"
        : "=v"(d) : "v"(a), "v"(b));
    return d;
}
__device__ __forceinline__ v2f pk_mul(v2f a, v2f b) {
    v2f d;
    asm("v_pk_mul_f32 %0, %1, %2" : "=v"(d) : "v"(a), "v"(b));
    return d;
}
__device__ __forceinline__ v2f pk_mul_swap(v2f a, v2f b) {   // a * b.yx
    v2f d;
    asm("v_pk_mul_f32 %0, %1, %2 op_sel:[0,1] op_sel_hi:[1,0]"
        : "=v"(d) : "v"(a), "v"(b));
    return d;
}
__device__ __forceinline__ v2f pk_fma(v2f a, v2f b, v2f c) {   // a*b + c
    v2f d;
    asm("v_pk_fma_f32 %0, %1, %2, %3" : "=v"(d) : "v"(a), "v"(b), "v"(c));
    return d;
}

// One circuit layer: unnormalized H on register-bit MC (1/sqrt2 folded into
// epilogue), then (X*RX if XGATE else RX) on bit MT where MC==1.
// ctv = (c,c), snv = (s,-s); off-diag = -i*s, so (-i*s)*z = snv * z.yx.
template <int MC, int MT, bool XGATE>
__device__ __forceinline__ void apply_layer(v2f* a, v2f ctv, v2f snv) {
#pragma unroll
    for (int i = 0; i < 16; ++i) {
        if (i & MC) continue;
        const int j = i | MC;
        const v2f t0 = a[i], t1 = a[j];
        a[i] = pk_add(t0, t1);
        a[j] = pk_sub(t0, t1);
    }
#pragma unroll
    for (int i = 0; i < 16; ++i) {
        if (!(i & MC) || (i & MT)) continue;   // control=1, target=0 slot
        const int j = i | MT;
        const v2f b0 = a[i], b1 = a[j];
        const v2f s0 = pk_mul_swap(snv, b0);   // snv * b0.yx
        const v2f s1 = pk_mul_swap(snv, b1);
        if (XGATE) {                           // X*RX = [[s, c],[c, s]]
            a[i] = pk_fma(ctv, b1, s0);
            a[j] = pk_fma(ctv, b0, s1);
        } else {                               // RX = [[c, s],[s, c]]
            a[i] = pk_fma(ctv, b0, s1);
            a[j] = pk_fma(ctv, b1, s0);
        }
    }
}

__global__ __launch_bounds__(TPB, 5) void qlayer_kernel(
        const float* __restrict__ state, const float* __restrict__ params,
        float* __restrict__ out) {
    __shared__ __align__(16) v2f amp[DIM];     // 32768 B exactly -> 5 blocks/CU
    char* const lds = (char*)amp;

    const int t = threadIdx.x;
    const int lane = t & 63;
    const long long sbase = (long long)blockIdx.x * DIM;

    // per-lane angle (lanes 0..11 hold cos/sin(theta_q/2)); broadcast via readlane
    const float th = params[lane < NQ ? lane : 0] * 0.5f;
    const float cl = cosf(th);
    const float sl = sinf(th);

    // ---- load 16 contiguous floats (64 B/thread) + norm reduction ----
    const float4* gp = (const float4*)(state + sbase + t * 16);
    float4 xv[4];
    float ss = 0.f;
#pragma unroll
    for (int j = 0; j < 4; ++j) {
        const float4 v = gp[j];
        xv[j] = v;
        ss = fmaf(v.x, v.x, ss); ss = fmaf(v.y, v.y, ss);
        ss = fmaf(v.z, v.z, ss); ss = fmaf(v.w, v.w, ss);
    }
    ss = wave_reduce(ss);
    if (lane == 0) ((float*)lds)[t >> 6] = ss;
    __syncthreads();                           // bar1: partials visible
    const float* redp = (const float*)lds;
    const float sst = redp[0] + redp[1] + redp[2] + redp[3];
    // invd = 1/(sqrt(sst)+1e-8) ~= rsq(sst): dropping +1e-8 is ~1.6e-10 rel.
    const float invd = __builtin_amdgcn_rsqf(sst);
    __syncthreads();                           // bar2: partials consumed

    // ---- encoding: re = clamp(v,-1,1); im = sign(v)*sqrt(1-re^2) ----
    // NOTE: the 3-way sign select must stay -- exact v==0 inputs are possible
    // (erfinv(2u-1) with u==0.5) and the reference maps them to im=0.
    // |q|^2 == 1 exactly => second normalization = 1/4096, folded into epilogue.
    v2f a[16];
#define ENC(k, xval)                                                      \
    {                                                                     \
        const float v   = (xval) * invd;                                  \
        const float re  = fminf(fmaxf(v, -1.0f), 1.0f);                   \
        const float imb = __builtin_amdgcn_sqrtf(fmaxf(1.0f - re * re, 0.f)); \
        const float im  = (v > 0.f) ? imb : ((v < 0.f) ? -imb : 0.f);     \
        v2f q; q.x = re; q.y = im;                                        \
        a[k] = q;                                                         \
    }
#pragma unroll
    for (int j = 0; j < 4; ++j) {
        const float4 xq = xv[j];
        ENC(4 * j + 0, xq.x); ENC(4 * j + 1, xq.y);
        ENC(4 * j + 2, xq.z); ENC(4 * j + 3, xq.w);
    }
#undef ENC

#define CTV(q) ({ v2f _c; _c.x = BCAST(cl, q); _c.y = _c.x; _c; })
#define SNV(q) ({ float _s = BCAST(sl, q); v2f _v; _v.x = _s; _v.y = -_s; _v; })

    // ---- pass 1: layers 0..2 on idx bits {0,1,2,3}; e = 16t + 2k + b0 ----
    apply_layer<1, 2, true>(a, CTV(0), SNV(0));
    apply_layer<2, 4, true>(a, CTV(1), SNV(1));
    apply_layer<4, 8, true>(a, CTV(2), SNV(2));
    {
        // e>>5 = t>>1; xor bits fold as byte = 128t | ((k ^ ((t>>1)&7))<<4)
        const int v1b = (t << 7) | (((t >> 1) & 7) << 4);
#pragma unroll
        for (int k = 0; k < 8; ++k) {
            v4f w; w.x = a[2 * k].x; w.y = a[2 * k].y;
            w.z = a[2 * k + 1].x; w.w = a[2 * k + 1].y;
            *(v4f*)(lds + (v1b ^ (k << 4))) = w;
        }
    }
    // NO barrier: P1 write / P2 read are wave-slab-local ([8192w, 8192w+8192))

    // ---- pass 2: layers 3..5 on idx bits {3,4,5,6}; e = (t&7) + 8r + 128g ----
    {
        // e>>5 = (r>>2) + 4g ; slot bit3 = (r&1)^(g&1), bits1-2 ^= (r>>2)
        const int g  = t >> 3;
        const int gp2 = g & 1;
        const int baseE = ((t & 7) << 3) + (g << 10) + (gp2 << 6);        // r even
        const int baseO = ((t & 7) << 3) + (g << 10) + ((1 - gp2) << 6);  // r odd
#pragma unroll
        for (int r = 0; r < 16; ++r)
            a[r] = *(const v2f*)(lds +
                ((((r & 1) ? baseO : baseE) ^ ((r >> 2) << 4)) + ((r >> 1) << 7)));
        apply_layer<1, 2, true>(a, CTV(3), SNV(3));
        apply_layer<2, 4, true>(a, CTV(4), SNV(4));
        apply_layer<4, 8, true>(a, CTV(5), SNV(5));
#pragma unroll
        for (int r = 0; r < 16; ++r)
            *(v2f*)(lds +
                ((((r & 1) ? baseO : baseE) ^ ((r >> 2) << 4)) + ((r >> 1) << 7))) = a[r];
    }
    // NO barrier: P2 write / P3 read are wave-slab-local

    // ---- pass 3: layers 6..8 on idx bits {6,7,8,9}; e = (t&63) + 64r + 1024w ----
    {
        // e>>5 = ((t>>5)&1) + 2r + 32w ; slot bit1 ^= (t>>5)&1, bits2-3 ^= r&3
        const int b3b = (((t & 63) ^ (((t >> 5) & 1) << 1)) << 3) + ((t >> 6) << 13);
#pragma unroll
        for (int r = 0; r < 16; ++r)
            a[r] = *(const v2f*)(lds + ((b3b ^ ((r & 3) << 5)) + (r << 9)));
        apply_layer<1, 2, true>(a, CTV(6), SNV(6));
        apply_layer<2, 4, true>(a, CTV(7), SNV(7));
        apply_layer<4, 8, true>(a, CTV(8), SNV(8));
#pragma unroll
        for (int r = 0; r < 16; ++r)
            *(v2f*)(lds + ((b3b ^ ((r & 3) << 5)) + (r << 9))) = a[r];
    }
    __syncthreads();   // bar3: REQUIRED -- P4 reads span all waves' slabs

    // ---- pass 4: layers 9..11 on idx bits {9,10,11,0}; e = 2t + 512k + b0 ----
    {
        // e>>5 = (t>>4) + 16k ; xor term depends only on t:
        // byte = (16t ^ (((t>>4)&7)<<4)) + 4096k ; (b0=0,b0=1) adjacent -> b128
        const int F0b = (t << 4) ^ (((t >> 4) & 7) << 4);
#pragma unroll
        for (int k = 0; k < 8; ++k) {
            const v4f v = *(const v4f*)(lds + (F0b + (k << 12)));
            v2f q0; q0.x = v.x; q0.y = v.y;
            v2f q1; q1.x = v.z; q1.y = v.w;
            a[k] = q0;       // bit0 = 0
            a[k + 8] = q1;   // bit0 = 1
        }
        apply_layer<1, 2, true >(a, CTV(9),  SNV(9));   // c=b9,  t=b10
        apply_layer<2, 4, true >(a, CTV(10), SNV(10));  // c=b10, t=b11
        apply_layer<4, 8, false>(a, CTV(11), SNV(11));  // c=b11, t=b0

        // probs epilogue; scale = 1/4096 (encode norm) * (1/sqrt2)^24 = 2^-24
        // non-temporal: 64 MB write stream, never re-read -> don't churn L2.
        v2f sc2; sc2.x = 0x1p-24f; sc2.y = 0x1p-24f;
        v2f* outp = (v2f*)(out + sbase);
#pragma unroll
        for (int k = 0; k < 8; ++k) {
            const v2f q0 = pk_mul(a[k], a[k]);
            const v2f q1 = pk_mul(a[k | 8], a[k | 8]);
            v2f res; res.x = q0.x + q0.y;
            res.y = q1.x + q1.y;
            res = pk_mul(res, sc2);
            __builtin_nontemporal_store(res, outp + t + (k << 8));
        }
    }
#undef CTV
#undef SNV
}

extern "C" void kernel_launch(void* const* d_in, const int* in_sizes, int n_in,
                              void* d_out, int out_size, void* d_ws, size_t ws_size,
                              hipStream_t stream) {
    (void)in_sizes; (void)n_in; (void)out_size; (void)d_ws; (void)ws_size;
    const float* state  = (const float*)d_in[0];   // (8,512,4096) fp32
    const float* params = (const float*)d_in[1];   // (12,) fp32
    float* out = (float*)d_out;                    // (8,512,4096) fp32
    qlayer_kernel<<<dim3(4096), dim3(TPB), 0, stream>>>(state, params, out);
}